// Round 1
// baseline (820.407 us; speedup 1.0000x reference)
//
#include <hip/hip_runtime.h>
#include <hip/hip_bf16.h>

#define EPSBN 1e-5f
#define NGRAPH 512

// ---------------------------------------------------------------------------
// Scatter-add aggregation: for each edge e, agg[dst[e]][f] += feat[src[e]][f].
// One thread per (edge, feature). F is a power of two. Optionally counts degree.
// ---------------------------------------------------------------------------
template <int F, bool DOCNT>
__global__ void __launch_bounds__(256) k_agg(
    const float* __restrict__ feat, const int* __restrict__ src,
    const int* __restrict__ dst, float* __restrict__ agg,
    float* __restrict__ cnt, int E)
{
    long long gid = (long long)blockIdx.x * 256 + threadIdx.x;
    int e = (int)(gid / F);
    int f = (int)(gid % F);
    if (e >= E) return;
    int s = src[e];
    int d = dst[e];
    atomicAdd(&agg[(long long)d * F + f], feat[(long long)s * F + f]);
    if (DOCNT && f == 0) atomicAdd(&cnt[d], 1.0f);
}

// ---------------------------------------------------------------------------
// t_out = relu( base + bias + xin_eff @ Wr ), accumulating column sum/sumsq.
//   PREAGG=true  (layer 1): base = (agg_row @ Wl) / cnt, xin_eff = xin (raw)
//   PREAGG=false (layers 2/3): base = m[row][j] / cnt, xin_eff = xin*a_in+c_in
// Grid-stride over row tiles; weights staged in LDS; per-thread stat
// accumulators flushed once per block (2 atomics per column per block).
// ---------------------------------------------------------------------------
template <int FIN, int FOUT, bool PREAGG>
__global__ void __launch_bounds__(256) k_sage_head(
    const float* __restrict__ xin,            // N x FIN
    const float* __restrict__ a_in,           // FIN (null if PREAGG)
    const float* __restrict__ c_in,           // FIN (null if PREAGG)
    const float* __restrict__ agg,            // PREAGG: N x FIN, else N x FOUT
    const float* __restrict__ cnt,            // N
    const float* __restrict__ Wl,             // FIN x FOUT (only if PREAGG)
    const float* __restrict__ bias,           // FOUT
    const float* __restrict__ Wr,             // FIN x FOUT
    float* __restrict__ tout,                 // N x FOUT (pre-BN, post-ReLU)
    float* __restrict__ s_out, float* __restrict__ q_out,
    int N)
{
    constexpr int RPP = 256 / FOUT;  // rows per pass
    __shared__ float sWr[FIN * FOUT];
    __shared__ float sWl[PREAGG ? FIN * FOUT : 4];
    __shared__ float sx[RPP * FIN];
    __shared__ float sm[PREAGG ? RPP * FIN : 4];
    __shared__ float sa[FIN], sc[FIN];
    __shared__ float red[256];

    for (int idx = threadIdx.x; idx < FIN * FOUT; idx += 256) {
        sWr[idx] = Wr[idx];
        if constexpr (PREAGG) sWl[idx] = Wl[idx];
    }
    if constexpr (!PREAGG) {
        for (int idx = threadIdx.x; idx < FIN; idx += 256) {
            sa[idx] = a_in[idx];
            sc[idx] = c_in[idx];
        }
    }

    const int r = threadIdx.x / FOUT;
    const int j = threadIdx.x % FOUT;
    float ssum = 0.f, ssq = 0.f;
    const int ntiles = (N + RPP - 1) / RPP;

    for (int tile = blockIdx.x; tile < ntiles; tile += gridDim.x) {
        const int row0 = tile * RPP;
        __syncthreads();  // protect previous pass's sx/sm reads + first-pass weights
        for (int idx = threadIdx.x; idx < RPP * FIN; idx += 256) {
            int rr = idx / FIN, kk = idx % FIN;
            int row = row0 + rr;
            float v = (row < N) ? xin[(long long)row * FIN + kk] : 0.f;
            if constexpr (!PREAGG) v = v * sa[kk] + sc[kk];
            sx[idx] = v;
            if constexpr (PREAGG)
                sm[idx] = (row < N) ? agg[(long long)row * FIN + kk] : 0.f;
        }
        __syncthreads();
        int row = row0 + r;
        if (row < N) {
            float invc = 1.f / fmaxf(cnt[row], 1.f);
            float acc = bias[j];
            if constexpr (PREAGG) {
                float accm = 0.f;
                #pragma unroll
                for (int k = 0; k < FIN; k++) {
                    acc  += sx[r * FIN + k] * sWr[k * FOUT + j];
                    accm += sm[r * FIN + k] * sWl[k * FOUT + j];
                }
                acc += accm * invc;  // (agg @ Wl)/cnt == (agg/cnt) @ Wl
            } else {
                acc += agg[(long long)row * FOUT + j] * invc;
                #pragma unroll
                for (int k = 0; k < FIN; k++)
                    acc += sx[r * FIN + k] * sWr[k * FOUT + j];
            }
            float v = fmaxf(acc, 0.f);
            tout[(long long)row * FOUT + j] = v;
            ssum += v;
            ssq += v * v;
        }
    }

    // block-level column stat reduction, then 2 atomics per column
    red[threadIdx.x] = ssum;
    __syncthreads();
    if (r == 0) {
        float tot = 0.f;
        for (int rr = 0; rr < RPP; rr++) tot += red[rr * FOUT + j];
        atomicAdd(&s_out[j], tot);
    }
    __syncthreads();
    red[threadIdx.x] = ssq;
    __syncthreads();
    if (r == 0) {
        float tot = 0.f;
        for (int rr = 0; rr < RPP; rr++) tot += red[rr * FOUT + j];
        atomicAdd(&q_out[j], tot);
    }
}

// ---------------------------------------------------------------------------
// y = (tin*a + c) @ W   (applies previous layer's BN affine on load)
// ---------------------------------------------------------------------------
template <int FIN, int FOUT>
__global__ void __launch_bounds__(256) k_transform(
    const float* __restrict__ tin, const float* __restrict__ a,
    const float* __restrict__ c, const float* __restrict__ W,
    float* __restrict__ y, int N)
{
    constexpr int RPP = 256 / FOUT;
    __shared__ float sW[FIN * FOUT];
    __shared__ float sx[RPP * FIN];
    __shared__ float sa[FIN], sc[FIN];
    for (int idx = threadIdx.x; idx < FIN * FOUT; idx += 256) sW[idx] = W[idx];
    for (int idx = threadIdx.x; idx < FIN; idx += 256) {
        sa[idx] = a[idx];
        sc[idx] = c[idx];
    }
    const int r = threadIdx.x / FOUT, j = threadIdx.x % FOUT;
    const int ntiles = (N + RPP - 1) / RPP;
    for (int tile = blockIdx.x; tile < ntiles; tile += gridDim.x) {
        const int row0 = tile * RPP;
        __syncthreads();
        for (int idx = threadIdx.x; idx < RPP * FIN; idx += 256) {
            int rr = idx / FIN, kk = idx % FIN;
            int row = row0 + rr;
            sx[idx] = (row < N) ? tin[(long long)row * FIN + kk] * sa[kk] + sc[kk] : 0.f;
        }
        __syncthreads();
        int row = row0 + r;
        if (row < N) {
            float acc = 0.f;
            #pragma unroll
            for (int k = 0; k < FIN; k++) acc += sx[r * FIN + k] * sW[k * FOUT + j];
            y[(long long)row * FOUT + j] = acc;
        }
    }
}

// ---------------------------------------------------------------------------
// BN affine finalize: a = g / sqrt(var+eps), c = be - mu*a
// ---------------------------------------------------------------------------
__global__ void k_finalize(const float* __restrict__ s, const float* __restrict__ q,
                           const float* __restrict__ g, const float* __restrict__ be,
                           float* __restrict__ a, float* __restrict__ c,
                           int F, float invN)
{
    int j = threadIdx.x;
    if (j < F) {
        float mu = s[j] * invN;
        float var = q[j] * invN - mu * mu;
        float aj = g[j] / sqrtf(var + EPSBN);
        a[j] = aj;
        c[j] = be[j] - mu * aj;
    }
}

// ---------------------------------------------------------------------------
// pooled[batch[i]][j] += t3[i][j]*a[j] + c[j]
// ---------------------------------------------------------------------------
__global__ void __launch_bounds__(256) k_pool(
    const float* __restrict__ t3, const float* __restrict__ a,
    const float* __restrict__ c, const int* __restrict__ batch,
    float* __restrict__ pooled, int N)
{
    long long gid = (long long)blockIdx.x * 256 + threadIdx.x;
    int i = (int)(gid >> 5);
    int j = (int)(gid & 31);
    if (i >= N) return;
    int g = batch[i];
    float v = t3[(long long)i * 32 + j] * a[j] + c[j];
    atomicAdd(&pooled[g * 32 + j], v);
}

// ---------------------------------------------------------------------------
// Per-graph MLP: 32 -> 128 relu -> 64 relu -> 2. One block (128 thr) per graph.
// ---------------------------------------------------------------------------
__global__ void __launch_bounds__(128) k_mlp(
    const float* __restrict__ pooled,
    const float* __restrict__ Wf1, const float* __restrict__ bf1,
    const float* __restrict__ Wf2, const float* __restrict__ bf2,
    const float* __restrict__ Wf3, const float* __restrict__ bf3,
    float* __restrict__ out)
{
    __shared__ float p[32], h1[128], h2[64];
    int g = blockIdx.x, t = threadIdx.x;
    if (t < 32) p[t] = pooled[g * 32 + t];
    __syncthreads();
    {
        float acc = bf1[t];
        #pragma unroll
        for (int k = 0; k < 32; k++) acc += p[k] * Wf1[k * 128 + t];
        h1[t] = fmaxf(acc, 0.f);
    }
    __syncthreads();
    if (t < 64) {
        float acc = bf2[t];
        #pragma unroll
        for (int k = 0; k < 128; k++) acc += h1[k] * Wf2[k * 64 + t];
        h2[t] = fmaxf(acc, 0.f);
    }
    __syncthreads();
    if (t < 2) {
        float acc = bf3[t];
        #pragma unroll
        for (int k = 0; k < 64; k++) acc += h2[k] * Wf3[k * 2 + t];
        out[g * 2 + t] = acc;
    }
}

// ---------------------------------------------------------------------------
extern "C" void kernel_launch(void* const* d_in, const int* in_sizes, int n_in,
                              void* d_out, int out_size, void* d_ws, size_t ws_size,
                              hipStream_t stream)
{
    const float* x     = (const float*)d_in[0];
    const int*   ei    = (const int*)d_in[1];
    const int*   batch = (const int*)d_in[2];
    const float* W1l = (const float*)d_in[3];
    const float* b1  = (const float*)d_in[4];
    const float* W1r = (const float*)d_in[5];
    const float* g1  = (const float*)d_in[6];
    const float* be1 = (const float*)d_in[7];
    const float* W2l = (const float*)d_in[8];
    const float* b2  = (const float*)d_in[9];
    const float* W2r = (const float*)d_in[10];
    const float* g2  = (const float*)d_in[11];
    const float* be2 = (const float*)d_in[12];
    const float* W3l = (const float*)d_in[13];
    const float* b3  = (const float*)d_in[14];
    const float* W3r = (const float*)d_in[15];
    const float* g3  = (const float*)d_in[16];
    const float* be3 = (const float*)d_in[17];
    const float* Wf1 = (const float*)d_in[18];
    const float* bf1 = (const float*)d_in[19];
    const float* Wf2 = (const float*)d_in[20];
    const float* bf2 = (const float*)d_in[21];
    const float* Wf3 = (const float*)d_in[22];
    const float* bf3 = (const float*)d_in[23];

    const int N = in_sizes[0] / 64;
    const int E = in_sizes[1] / 2;
    const int* src = ei;
    const int* dst = ei + E;

    // ---- workspace layout (with aliasing) ----
    char* ws = (char*)d_ws;
    size_t off = 0;
    auto alloc = [&](size_t bytes) {
        size_t o = off;
        off += (bytes + 511) & ~(size_t)511;
        return o;
    };
    const size_t o_cnt   = alloc((size_t)N * 4);
    const size_t o_agg1  = alloc((size_t)N * 64 * 4);   // also m2
    const size_t o_t1    = alloc((size_t)N * 128 * 4);  // also y3 / m3 / t3
    const size_t o_y2    = alloc((size_t)N * 64 * 4);   // also t2
    const size_t o_pool  = alloc((size_t)NGRAPH * 32 * 4);
    const size_t o_stats = alloc(448 * 4);
    const size_t o_aff   = alloc(448 * 4);
    (void)ws_size;

    float* cnt  = (float*)(ws + o_cnt);
    float* agg1 = (float*)(ws + o_agg1);
    float* m2   = agg1;                       // alias (re-zeroed mid-stream)
    float* t1   = (float*)(ws + o_t1);
    float* y3   = t1;                         // alias after t1 consumed
    float* m3   = t1 + (size_t)N * 32;
    float* t3   = t1 + (size_t)N * 64;
    float* y2   = (float*)(ws + o_y2);
    float* t2   = y2;                         // alias (y2 dead once t2 written)
    float* pooled = (float*)(ws + o_pool);
    float* s1 = (float*)(ws + o_stats);
    float* q1 = s1 + 128;
    float* s2 = q1 + 128;
    float* q2 = s2 + 64;
    float* s3 = q2 + 64;
    float* q3 = s3 + 32;
    float* a1 = (float*)(ws + o_aff);
    float* c1 = a1 + 128;
    float* a2 = c1 + 128;
    float* c2 = a2 + 64;
    float* a3 = c2 + 64;
    float* c3 = a3 + 32;

    const float invN = 1.0f / (float)N;
    const int GS = 1024;  // grid-stride block count for dense kernels

    // ---- zero accumulators ----
    hipMemsetAsync(ws + o_cnt, 0, (size_t)N * 4, stream);
    hipMemsetAsync(ws + o_agg1, 0, (size_t)N * 64 * 4, stream);
    hipMemsetAsync(ws + o_stats, 0, 448 * 4, stream);
    hipMemsetAsync(ws + o_pool, 0, (size_t)NGRAPH * 32 * 4, stream);

    // ---- layer 1 ----
    {
        long long tot = (long long)E * 64;
        int blocks = (int)((tot + 255) / 256);
        k_agg<64, true><<<blocks, 256, 0, stream>>>(x, src, dst, agg1, cnt, E);
    }
    k_sage_head<64, 128, true><<<GS, 256, 0, stream>>>(
        x, nullptr, nullptr, agg1, cnt, W1l, b1, W1r, t1, s1, q1, N);
    k_finalize<<<1, 128, 0, stream>>>(s1, q1, g1, be1, a1, c1, 128, invN);

    // ---- layer 2 (transform-first aggregation) ----
    k_transform<128, 64><<<GS, 256, 0, stream>>>(t1, a1, c1, W2l, y2, N);
    hipMemsetAsync((void*)m2, 0, (size_t)N * 64 * 4, stream);
    {
        long long tot = (long long)E * 64;
        int blocks = (int)((tot + 255) / 256);
        k_agg<64, false><<<blocks, 256, 0, stream>>>(y2, src, dst, m2, nullptr, E);
    }
    k_sage_head<128, 64, false><<<GS, 256, 0, stream>>>(
        t1, a1, c1, m2, cnt, nullptr, b2, W2r, t2, s2, q2, N);
    k_finalize<<<1, 64, 0, stream>>>(s2, q2, g2, be2, a2, c2, 64, invN);

    // ---- layer 3 ----
    k_transform<64, 32><<<GS, 256, 0, stream>>>(t2, a2, c2, W3l, y3, N);
    hipMemsetAsync((void*)m3, 0, (size_t)N * 32 * 4, stream);
    {
        long long tot = (long long)E * 32;
        int blocks = (int)((tot + 255) / 256);
        k_agg<32, false><<<blocks, 256, 0, stream>>>(y3, src, dst, m3, nullptr, E);
    }
    k_sage_head<64, 32, false><<<GS, 256, 0, stream>>>(
        t2, a2, c2, m3, cnt, nullptr, b3, W3r, t3, s3, q3, N);
    k_finalize<<<1, 32, 0, stream>>>(s3, q3, g3, be3, a3, c3, 32, invN);

    // ---- pool + MLP ----
    {
        long long tot = (long long)N * 32;
        int blocks = (int)((tot + 255) / 256);
        k_pool<<<blocks, 256, 0, stream>>>(t3, a3, c3, batch, pooled, N);
    }
    k_mlp<<<NGRAPH, 128, 0, stream>>>(pooled, Wf1, bf1, Wf2, bf2, Wf3, bf3,
                                      (float*)d_out);
}

// Round 2
// 618.045 us; speedup vs baseline: 1.3274x; 1.3274x over previous
//
#include <hip/hip_runtime.h>
#include <hip/hip_bf16.h>

#define EPSBN 1e-5f
#define NGRAPH 512

struct f4 { float x, y, z, w; };
__device__ inline void f4add(f4& a, const float4& b) {
    a.x += b.x; a.y += b.y; a.z += b.z; a.w += b.w;
}

// ---------------------------------------------------------------------------
// CSR build step 1: histogram of dst
// ---------------------------------------------------------------------------
__global__ void __launch_bounds__(256) k_hist(
    const int* __restrict__ dst, int* __restrict__ hist, int E)
{
    for (int e = blockIdx.x * 256 + threadIdx.x; e < E; e += gridDim.x * 256)
        atomicAdd(&hist[dst[e]], 1);
}

// ---------------------------------------------------------------------------
// CSR build step 2: single-block exclusive prefix scan of hist (N<=~1M)
// writes row_off[0..N] and cursor[0..N-1]
// ---------------------------------------------------------------------------
__global__ void __launch_bounds__(1024) k_scan(
    const int* __restrict__ hist, int* __restrict__ row_off,
    int* __restrict__ cursor, int N)
{
    __shared__ int part[1024];
    const int t = threadIdx.x;
    const int C = (N + 1023) / 1024;
    const int c0 = t * C;
    const int c1 = min(c0 + C, N);
    int s = 0;
    for (int i = c0; i < c1; i++) s += hist[i];
    part[t] = s;
    __syncthreads();
    for (int off = 1; off < 1024; off <<= 1) {
        int v = (t >= off) ? part[t - off] : 0;
        __syncthreads();
        part[t] += v;
        __syncthreads();
    }
    int run = part[t] - s;  // exclusive prefix
    for (int i = c0; i < c1; i++) {
        row_off[i] = run;
        cursor[i] = run;
        run += hist[i];
    }
    if (t == 0) row_off[N] = part[1023];
}

// ---------------------------------------------------------------------------
// CSR build step 3: scatter src ids into per-dst slots
// ---------------------------------------------------------------------------
__global__ void __launch_bounds__(256) k_scatter(
    const int* __restrict__ src, const int* __restrict__ dst,
    int* __restrict__ cursor, int* __restrict__ csr, int E)
{
    for (int e = blockIdx.x * 256 + threadIdx.x; e < E; e += gridDim.x * 256) {
        int d = dst[e];
        int p = atomicAdd(&cursor[d], 1);
        csr[p] = src[e];
    }
}

// ---------------------------------------------------------------------------
// Gather-aggregate: agg[i][:] = sum over neighbors s of feat[s][:]
// F/4 lanes per row (float4), 256/(F/4) rows per block.
// ---------------------------------------------------------------------------
template <int F>
__global__ void __launch_bounds__(256) k_gather(
    const float* __restrict__ feat, const int* __restrict__ row_off,
    const int* __restrict__ csr, float* __restrict__ agg, int N)
{
    constexpr int LPR = F / 4;        // lanes per row
    constexpr int RPB = 256 / LPR;    // rows per block
    const int lane = threadIdx.x % LPR;
    const int rloc = threadIdx.x / LPR;
    for (int row = blockIdx.x * RPB + rloc; row < N; row += gridDim.x * RPB) {
        const int s0 = row_off[row];
        const int s1 = row_off[row + 1];
        f4 acc0 = {0, 0, 0, 0}, acc1 = {0, 0, 0, 0};
        int p = s0;
        for (; p + 1 < s1; p += 2) {
            int sA = csr[p];
            int sB = csr[p + 1];
            f4add(acc0, *(const float4*)&feat[(long long)sA * F + lane * 4]);
            f4add(acc1, *(const float4*)&feat[(long long)sB * F + lane * 4]);
        }
        if (p < s1) {
            int sA = csr[p];
            f4add(acc0, *(const float4*)&feat[(long long)sA * F + lane * 4]);
        }
        float4 out;
        out.x = acc0.x + acc1.x; out.y = acc0.y + acc1.y;
        out.z = acc0.z + acc1.z; out.w = acc0.w + acc1.w;
        *(float4*)&agg[(long long)row * F + lane * 4] = out;
    }
}

// ---------------------------------------------------------------------------
// t_out = relu( base + bias + xin_eff @ Wr ), accumulating column sum/sumsq.
//   PREAGG=true  (layer 1): base = (agg_row @ Wl) / cnt, xin_eff = xin (raw)
//   PREAGG=false (layers 2/3): base = m[row][j] / cnt, xin_eff = xin*a_in+c_in
// cnt comes from row_off diffs.
// ---------------------------------------------------------------------------
template <int FIN, int FOUT, bool PREAGG>
__global__ void __launch_bounds__(256) k_sage_head(
    const float* __restrict__ xin,            // N x FIN
    const float* __restrict__ a_in,           // FIN (null if PREAGG)
    const float* __restrict__ c_in,           // FIN (null if PREAGG)
    const float* __restrict__ agg,            // PREAGG: N x FIN, else N x FOUT
    const int* __restrict__ row_off,          // N+1
    const float* __restrict__ Wl,             // FIN x FOUT (only if PREAGG)
    const float* __restrict__ bias,           // FOUT
    const float* __restrict__ Wr,             // FIN x FOUT
    float* __restrict__ tout,                 // N x FOUT (pre-BN, post-ReLU)
    float* __restrict__ s_out, float* __restrict__ q_out,
    int N)
{
    constexpr int RPP = 256 / FOUT;  // rows per pass
    __shared__ float sWr[FIN * FOUT];
    __shared__ float sWl[PREAGG ? FIN * FOUT : 4];
    __shared__ float sx[RPP * FIN];
    __shared__ float sm[PREAGG ? RPP * FIN : 4];
    __shared__ float sa[FIN], sc[FIN];
    __shared__ float red[256];

    for (int idx = threadIdx.x; idx < FIN * FOUT; idx += 256) {
        sWr[idx] = Wr[idx];
        if constexpr (PREAGG) sWl[idx] = Wl[idx];
    }
    if constexpr (!PREAGG) {
        for (int idx = threadIdx.x; idx < FIN; idx += 256) {
            sa[idx] = a_in[idx];
            sc[idx] = c_in[idx];
        }
    }

    const int r = threadIdx.x / FOUT;
    const int j = threadIdx.x % FOUT;
    float ssum = 0.f, ssq = 0.f;
    const int ntiles = (N + RPP - 1) / RPP;

    for (int tile = blockIdx.x; tile < ntiles; tile += gridDim.x) {
        const int row0 = tile * RPP;
        __syncthreads();  // protect previous pass's sx/sm reads + first-pass weights
        for (int idx = threadIdx.x; idx < RPP * FIN; idx += 256) {
            int rr = idx / FIN, kk = idx % FIN;
            int row = row0 + rr;
            float v = (row < N) ? xin[(long long)row * FIN + kk] : 0.f;
            if constexpr (!PREAGG) v = v * sa[kk] + sc[kk];
            sx[idx] = v;
            if constexpr (PREAGG)
                sm[idx] = (row < N) ? agg[(long long)row * FIN + kk] : 0.f;
        }
        __syncthreads();
        int row = row0 + r;
        if (row < N) {
            int cnt = row_off[row + 1] - row_off[row];
            float invc = 1.f / (float)max(cnt, 1);
            float acc = bias[j];
            if constexpr (PREAGG) {
                float accm = 0.f;
                #pragma unroll
                for (int k = 0; k < FIN; k++) {
                    acc  += sx[r * FIN + k] * sWr[k * FOUT + j];
                    accm += sm[r * FIN + k] * sWl[k * FOUT + j];
                }
                acc += accm * invc;  // (agg @ Wl)/cnt == (agg/cnt) @ Wl
            } else {
                acc += agg[(long long)row * FOUT + j] * invc;
                #pragma unroll
                for (int k = 0; k < FIN; k++)
                    acc += sx[r * FIN + k] * sWr[k * FOUT + j];
            }
            float v = fmaxf(acc, 0.f);
            tout[(long long)row * FOUT + j] = v;
            ssum += v;
            ssq += v * v;
        }
    }

    // block-level column stat reduction, then 2 atomics per column
    red[threadIdx.x] = ssum;
    __syncthreads();
    if (r == 0) {
        float tot = 0.f;
        for (int rr = 0; rr < RPP; rr++) tot += red[rr * FOUT + j];
        atomicAdd(&s_out[j], tot);
    }
    __syncthreads();
    red[threadIdx.x] = ssq;
    __syncthreads();
    if (r == 0) {
        float tot = 0.f;
        for (int rr = 0; rr < RPP; rr++) tot += red[rr * FOUT + j];
        atomicAdd(&q_out[j], tot);
    }
}

// ---------------------------------------------------------------------------
// y = (tin*a + c) @ W   (applies previous layer's BN affine on load)
// ---------------------------------------------------------------------------
template <int FIN, int FOUT>
__global__ void __launch_bounds__(256) k_transform(
    const float* __restrict__ tin, const float* __restrict__ a,
    const float* __restrict__ c, const float* __restrict__ W,
    float* __restrict__ y, int N)
{
    constexpr int RPP = 256 / FOUT;
    __shared__ float sW[FIN * FOUT];
    __shared__ float sx[RPP * FIN];
    __shared__ float sa[FIN], sc[FIN];
    for (int idx = threadIdx.x; idx < FIN * FOUT; idx += 256) sW[idx] = W[idx];
    for (int idx = threadIdx.x; idx < FIN; idx += 256) {
        sa[idx] = a[idx];
        sc[idx] = c[idx];
    }
    const int r = threadIdx.x / FOUT, j = threadIdx.x % FOUT;
    const int ntiles = (N + RPP - 1) / RPP;
    for (int tile = blockIdx.x; tile < ntiles; tile += gridDim.x) {
        const int row0 = tile * RPP;
        __syncthreads();
        for (int idx = threadIdx.x; idx < RPP * FIN; idx += 256) {
            int rr = idx / FIN, kk = idx % FIN;
            int row = row0 + rr;
            sx[idx] = (row < N) ? tin[(long long)row * FIN + kk] * sa[kk] + sc[kk] : 0.f;
        }
        __syncthreads();
        int row = row0 + r;
        if (row < N) {
            float acc = 0.f;
            #pragma unroll
            for (int k = 0; k < FIN; k++) acc += sx[r * FIN + k] * sW[k * FOUT + j];
            y[(long long)row * FOUT + j] = acc;
        }
    }
}

// ---------------------------------------------------------------------------
// BN affine finalize: a = g / sqrt(var+eps), c = be - mu*a
// ---------------------------------------------------------------------------
__global__ void k_finalize(const float* __restrict__ s, const float* __restrict__ q,
                           const float* __restrict__ g, const float* __restrict__ be,
                           float* __restrict__ a, float* __restrict__ c,
                           int F, float invN)
{
    int j = threadIdx.x;
    if (j < F) {
        float mu = s[j] * invN;
        float var = q[j] * invN - mu * mu;
        float aj = g[j] / sqrtf(var + EPSBN);
        a[j] = aj;
        c[j] = be[j] - mu * aj;
    }
}

// ---------------------------------------------------------------------------
// pooled[batch[i]][j] += t3[i][j]*a[j] + c[j]
// ---------------------------------------------------------------------------
__global__ void __launch_bounds__(256) k_pool(
    const float* __restrict__ t3, const float* __restrict__ a,
    const float* __restrict__ c, const int* __restrict__ batch,
    float* __restrict__ pooled, int N)
{
    long long gid = (long long)blockIdx.x * 256 + threadIdx.x;
    int i = (int)(gid >> 5);
    int j = (int)(gid & 31);
    if (i >= N) return;
    int g = batch[i];
    float v = t3[(long long)i * 32 + j] * a[j] + c[j];
    atomicAdd(&pooled[g * 32 + j], v);
}

// ---------------------------------------------------------------------------
// Per-graph MLP: 32 -> 128 relu -> 64 relu -> 2. One block (128 thr) per graph.
// ---------------------------------------------------------------------------
__global__ void __launch_bounds__(128) k_mlp(
    const float* __restrict__ pooled,
    const float* __restrict__ Wf1, const float* __restrict__ bf1,
    const float* __restrict__ Wf2, const float* __restrict__ bf2,
    const float* __restrict__ Wf3, const float* __restrict__ bf3,
    float* __restrict__ out)
{
    __shared__ float p[32], h1[128], h2[64];
    int g = blockIdx.x, t = threadIdx.x;
    if (t < 32) p[t] = pooled[g * 32 + t];
    __syncthreads();
    {
        float acc = bf1[t];
        #pragma unroll
        for (int k = 0; k < 32; k++) acc += p[k] * Wf1[k * 128 + t];
        h1[t] = fmaxf(acc, 0.f);
    }
    __syncthreads();
    if (t < 64) {
        float acc = bf2[t];
        #pragma unroll
        for (int k = 0; k < 128; k++) acc += h1[k] * Wf2[k * 64 + t];
        h2[t] = fmaxf(acc, 0.f);
    }
    __syncthreads();
    if (t < 2) {
        float acc = bf3[t];
        #pragma unroll
        for (int k = 0; k < 64; k++) acc += h2[k] * Wf3[k * 2 + t];
        out[g * 2 + t] = acc;
    }
}

// ---------------------------------------------------------------------------
extern "C" void kernel_launch(void* const* d_in, const int* in_sizes, int n_in,
                              void* d_out, int out_size, void* d_ws, size_t ws_size,
                              hipStream_t stream)
{
    const float* x     = (const float*)d_in[0];
    const int*   ei    = (const int*)d_in[1];
    const int*   batch = (const int*)d_in[2];
    const float* W1l = (const float*)d_in[3];
    const float* b1  = (const float*)d_in[4];
    const float* W1r = (const float*)d_in[5];
    const float* g1  = (const float*)d_in[6];
    const float* be1 = (const float*)d_in[7];
    const float* W2l = (const float*)d_in[8];
    const float* b2  = (const float*)d_in[9];
    const float* W2r = (const float*)d_in[10];
    const float* g2  = (const float*)d_in[11];
    const float* be2 = (const float*)d_in[12];
    const float* W3l = (const float*)d_in[13];
    const float* b3  = (const float*)d_in[14];
    const float* W3r = (const float*)d_in[15];
    const float* g3  = (const float*)d_in[16];
    const float* be3 = (const float*)d_in[17];
    const float* Wf1 = (const float*)d_in[18];
    const float* bf1 = (const float*)d_in[19];
    const float* Wf2 = (const float*)d_in[20];
    const float* bf2 = (const float*)d_in[21];
    const float* Wf3 = (const float*)d_in[22];
    const float* bf3 = (const float*)d_in[23];

    const int N = in_sizes[0] / 64;
    const int E = in_sizes[1] / 2;
    const int* src = ei;
    const int* dst = ei + E;

    // ---- workspace layout (with aliasing) ----
    char* ws = (char*)d_ws;
    size_t off = 0;
    auto alloc = [&](size_t bytes) {
        size_t o = off;
        off += (bytes + 511) & ~(size_t)511;
        return o;
    };
    const size_t o_rowoff = alloc((size_t)(N + 1) * 4);
    const size_t o_hist   = alloc((size_t)N * 4);
    const size_t o_cursor = alloc((size_t)N * 4);
    const size_t o_csr    = alloc((size_t)E * 4);
    const size_t o_agg1   = alloc((size_t)N * 64 * 4);   // also m2
    const size_t o_t1     = alloc((size_t)N * 128 * 4);  // also y3 / m3 / t3
    const size_t o_y2     = alloc((size_t)N * 64 * 4);   // also t2
    const size_t o_pool   = alloc((size_t)NGRAPH * 32 * 4);
    const size_t o_stats  = alloc(448 * 4);
    const size_t o_aff    = alloc(448 * 4);
    (void)ws_size;

    int* row_off = (int*)(ws + o_rowoff);
    int* hist    = (int*)(ws + o_hist);
    int* cursor  = (int*)(ws + o_cursor);
    int* csr     = (int*)(ws + o_csr);
    float* agg1 = (float*)(ws + o_agg1);
    float* m2   = agg1;                       // alias (gather overwrites fully)
    float* t1   = (float*)(ws + o_t1);
    float* y3   = t1;                         // alias after t1 consumed
    float* m3   = t1 + (size_t)N * 32;
    float* t3   = t1 + (size_t)N * 64;
    float* y2   = (float*)(ws + o_y2);
    float* t2   = y2;                         // alias (y2 dead once t2 written)
    float* pooled = (float*)(ws + o_pool);
    float* s1 = (float*)(ws + o_stats);
    float* q1 = s1 + 128;
    float* s2 = q1 + 128;
    float* q2 = s2 + 64;
    float* s3 = q2 + 64;
    float* q3 = s3 + 32;
    float* a1 = (float*)(ws + o_aff);
    float* c1 = a1 + 128;
    float* a2 = c1 + 128;
    float* c2 = a2 + 64;
    float* a3 = c2 + 64;
    float* c3 = a3 + 32;

    const float invN = 1.0f / (float)N;
    const int GS = 1024;  // grid-stride block count for dense kernels

    // ---- zero accumulators ----
    hipMemsetAsync(ws + o_hist, 0, (size_t)N * 4, stream);
    hipMemsetAsync(ws + o_stats, 0, 448 * 4, stream);
    hipMemsetAsync(ws + o_pool, 0, (size_t)NGRAPH * 32 * 4, stream);

    // ---- CSR build (amortized over 3 aggregations) ----
    k_hist<<<2048, 256, 0, stream>>>(dst, hist, E);
    k_scan<<<1, 1024, 0, stream>>>(hist, row_off, cursor, N);
    k_scatter<<<2048, 256, 0, stream>>>(src, dst, cursor, csr, E);

    // ---- layer 1 ----
    k_gather<64><<<(N + 15) / 16, 256, 0, stream>>>(x, row_off, csr, agg1, N);
    k_sage_head<64, 128, true><<<GS, 256, 0, stream>>>(
        x, nullptr, nullptr, agg1, row_off, W1l, b1, W1r, t1, s1, q1, N);
    k_finalize<<<1, 128, 0, stream>>>(s1, q1, g1, be1, a1, c1, 128, invN);

    // ---- layer 2 (transform-first aggregation) ----
    k_transform<128, 64><<<GS, 256, 0, stream>>>(t1, a1, c1, W2l, y2, N);
    k_gather<64><<<(N + 15) / 16, 256, 0, stream>>>(y2, row_off, csr, m2, N);
    k_sage_head<128, 64, false><<<GS, 256, 0, stream>>>(
        t1, a1, c1, m2, row_off, nullptr, b2, W2r, t2, s2, q2, N);
    k_finalize<<<1, 64, 0, stream>>>(s2, q2, g2, be2, a2, c2, 64, invN);

    // ---- layer 3 ----
    k_transform<64, 32><<<GS, 256, 0, stream>>>(t2, a2, c2, W3l, y3, N);
    k_gather<32><<<(N + 31) / 32, 256, 0, stream>>>(y3, row_off, csr, m3, N);
    k_sage_head<64, 32, false><<<GS, 256, 0, stream>>>(
        t2, a2, c2, m3, row_off, nullptr, b3, W3r, t3, s3, q3, N);
    k_finalize<<<1, 32, 0, stream>>>(s3, q3, g3, be3, a3, c3, 32, invN);

    // ---- pool + MLP ----
    {
        long long tot = (long long)N * 32;
        int blocks = (int)((tot + 255) / 256);
        k_pool<<<blocks, 256, 0, stream>>>(t3, a3, c3, batch, pooled, N);
    }
    k_mlp<<<NGRAPH, 128, 0, stream>>>(pooled, Wf1, bf1, Wf2, bf2, Wf3, bf3,
                                      (float*)d_out);
}